// Round 13
// baseline (184.704 us; speedup 1.0000x reference)
//
#include <hip/hip_runtime.h>
#include <math.h>

#define N_NODES 50000
#define N_EDGES 800000
#define C 128
#define NT 3
#define NEG 0.2f
#define CAP 64   // max in-edges per node kept (Poisson(16): max observed degree ~45)

#define GEMM_XB 782          // ceil(N_NODES/64)
#define NCHUNK 782           // edge chunks of 1024 (last partial: 256)

typedef __attribute__((ext_vector_type(8))) short short8;   // 8 bf16 = 4 VGPRs
typedef __attribute__((ext_vector_type(4))) float f32x4;
typedef __attribute__((ext_vector_type(4))) int i32x4;

__device__ __forceinline__ float leaky(float v) { return v > 0.f ? v : NEG * v; }

__device__ __forceinline__ unsigned short f2bf(float f) {
  unsigned int u = __float_as_uint(f);
  u = (u + 0x7FFFu + ((u >> 16) & 1u)) >> 16;   // RNE
  return (unsigned short)u;
}
__device__ __forceinline__ float bf_lo(unsigned int w) { return __uint_as_float(w << 16); }
__device__ __forceinline__ float bf_hi(unsigned int w) { return __uint_as_float(w & 0xFFFF0000u); }

// ---------------- prep: Wt[t][n][k] = bf16(W[t][k][n])  ||  cnt = 0 ----------------
__global__ void k_prep(const float* __restrict__ W, unsigned short* __restrict__ Wt,
                       int* __restrict__ cnt) {
  int bid = blockIdx.x;
  if (bid < 192) {
    int idx = bid * 256 + threadIdx.x;          // 3*128*128 = 49152 elements
    int t = idx >> 14, rem = idx & 16383;
    int n = rem >> 7, k = rem & 127;
    Wt[((size_t)t * C + n) * C + k] = f2bf(W[((size_t)t * C + k) * C + n]);
  } else {
    int i4 = (bid - 192) * 256 + threadIdx.x;   // 12500 int4 = 50000 ints
    if (i4 < N_NODES / 4) ((int4*)cnt)[i4] = make_int4(0, 0, 0, 0);
  }
}

// ---------------- fused SEGREGATED bin || mm (R12: exact R8 + NT edge loads ONLY) ----------------
// R12 reproduced R8 (180.3us total, k_bm 57-62us, WRITE 81MB) -> R10/R11 were infra.
// Residual slack: WRITE 81MB vs ~44MB audited floor. The ~36MB amp sits on bin's
// ~4MB bucket payload (~9x dirty-line bounce): a node's ~16 entries arrive spread
// over the whole 45us scan, so its 64B line must stay L2-resident the whole kernel,
// but the 9.6MB streaming edge-read traffic LRU-evicts partial bucket lines. R9's
// NT-load test was confounded (bundled with 52KB LDS + NT stores, both regressions).
// THIS ROUND = single variable: __builtin_nontemporal_load on the 3 edge-stream
// loads (nt = evict-first -> streams leave L2 first, bucket lines survive to merge).
// Decisive check: WRITE 81 -> ~48-55MB. If WRITE unchanged, nt doesn't protect L2
// residency on gfx950 -> next is ushort-packed buckets or plateau.
// Standing structure (R0/R5/R8 lessons): segregation (bin odd XCDs / mm even),
// dst-range class ownership, A in regs once, B via LDS per t.
__global__ void k_bm(const float* __restrict__ x, const int* __restrict__ node_type,
                     const float* __restrict__ emb, const unsigned short* __restrict__ Wt,
                     unsigned short* __restrict__ xwb,
                     const float* __restrict__ att_src, const float* __restrict__ att_dst,
                     float* __restrict__ a_s, float2* __restrict__ ad_es,
                     const int* __restrict__ ei, const int* __restrict__ etype,
                     int* __restrict__ cnt, int* __restrict__ buckets) {
  __shared__ unsigned short Bs[128][136];   // +8 halfword pad (proven R0 layout)
  const int bid = blockIdx.x;
  const int tid = threadIdx.x;

  if (bid & 1) {
    // ---- bin role (XCDs 1,3,5,7): class owns contiguous 12500-dst range ----
    const int j = bid >> 1;                  // 0..781
    const int c = j & 3;                     // == ((bid%8)>>1): stable per XCD
    const int i = j >> 2;                    // index within class
    const int n_c = (c < 2) ? 196 : 195;     // blocks in this class
    const int dlo = c * 12500, dhi = dlo + 12500;
    for (int cc = i; cc < NCHUNK; cc += n_c) {       // strided chunk coverage
      int e0 = cc * 1024 + tid * 4;
      if (e0 + 4 <= N_EDGES) {               // N_EDGES%4==0: full quad or nothing
        i32x4 s4 = __builtin_nontemporal_load((const i32x4*)(ei + e0));
        i32x4 d4 = __builtin_nontemporal_load((const i32x4*)(ei + N_EDGES + e0));
        i32x4 t4 = __builtin_nontemporal_load((const i32x4*)(etype + e0));
        if (d4[0] >= dlo && d4[0] < dhi) {
          int p = atomicAdd(&cnt[d4[0]], 1);
          if (p < CAP) buckets[(size_t)d4[0] * CAP + p] = t4[0] * N_NODES + s4[0];
        }
        if (d4[1] >= dlo && d4[1] < dhi) {
          int p = atomicAdd(&cnt[d4[1]], 1);
          if (p < CAP) buckets[(size_t)d4[1] * CAP + p] = t4[1] * N_NODES + s4[1];
        }
        if (d4[2] >= dlo && d4[2] < dhi) {
          int p = atomicAdd(&cnt[d4[2]], 1);
          if (p < CAP) buckets[(size_t)d4[2] * CAP + p] = t4[2] * N_NODES + s4[2];
        }
        if (d4[3] >= dlo && d4[3] < dhi) {
          int p = atomicAdd(&cnt[d4[3]], 1);
          if (p < CAP) buckets[(size_t)d4[3] * CAP + p] = t4[3] * N_NODES + s4[3];
        }
      }
    }
    return;
  }

  // ---- mm role (XCDs 0,2,4,6): one 64-row block, t-loop, A in regs once ----
  const int rb = bid >> 1;                   // 0..781
  const int wid = tid >> 6, lane = tid & 63;
  const int m = lane & 15, quad = lane >> 4;
  const int row0 = rb * 64;

  // A fragments in registers, t-invariant: lane (wid,m,quad) owns row wid*16+m,
  // k-chunks {k0i*32 + quad*8 .. +8}. bf16(x + emb[node_type]).
  short8 af[4];
  {
    int arow = row0 + wid * 16 + m;
    bool valid = arow < N_NODES;
    const float* xr = x + (size_t)(valid ? arow : 0) * C;   // row 0 if invalid; stores guarded
    int nt = valid ? node_type[arow] : 0;
    const float* er = emb + nt * C;
#pragma unroll
    for (int k0i = 0; k0i < 4; ++k0i) {
      int cb = k0i * 32 + quad * 8;
      float4 v0 = *(const float4*)(xr + cb);
      float4 v1 = *(const float4*)(xr + cb + 4);
      float4 e0 = *(const float4*)(er + cb);
      float4 e1 = *(const float4*)(er + cb + 4);
      short8 f;
      f[0] = (short)f2bf(v0.x + e0.x);
      f[1] = (short)f2bf(v0.y + e0.y);
      f[2] = (short)f2bf(v0.z + e0.z);
      f[3] = (short)f2bf(v0.w + e0.w);
      f[4] = (short)f2bf(v1.x + e1.x);
      f[5] = (short)f2bf(v1.y + e1.y);
      f[6] = (short)f2bf(v1.z + e1.z);
      f[7] = (short)f2bf(v1.w + e1.w);
      af[k0i] = f;
    }
  }

  // stage B for t=0 (32KB, L2-hot: same 96KB Wt read by all mm blocks)
#pragma unroll
  for (int it = 0; it < 8; ++it) {
    int c = tid + it * 256;
    int n = c >> 4, kc = c & 15;
    *(uint4*)&Bs[n][kc * 8] = *(const uint4*)(Wt + (size_t)n * C + kc * 8);
  }
  __syncthreads();

  for (int t = 0; t < NT; ++t) {
    f32x4 acc[8] = {};
#pragma unroll
    for (int k0i = 0; k0i < 4; ++k0i) {
      int k0 = k0i * 32;
#pragma unroll
      for (int j = 0; j < 8; ++j) {
        short8 b = *(const short8*)&Bs[j * 16 + m][k0 + quad * 8];
        acc[j] = __builtin_amdgcn_mfma_f32_16x16x32_bf16(af[k0i], b, acc[j], 0, 0, 0);
      }
    }

    // epilogue: write xw (bf16) + fused attention logits (registers/shuffles only)
    float ps[4] = {}, pd[4] = {};
#pragma unroll
    for (int j = 0; j < 8; ++j) {
      float as = att_src[t * C + j * 16 + m];
      float ad = att_dst[t * C + j * 16 + m];
#pragma unroll
      for (int reg = 0; reg < 4; ++reg) {
        int row = row0 + wid * 16 + quad * 4 + reg;
        float v = acc[j][reg];
        if (row < N_NODES) xwb[((size_t)t * N_NODES + row) * C + j * 16 + m] = f2bf(v);
        ps[reg] += v * as;
        pd[reg] += v * ad;
      }
    }
#pragma unroll
    for (int off = 1; off < 16; off <<= 1) {
#pragma unroll
      for (int reg = 0; reg < 4; ++reg) {
        ps[reg] += __shfl_xor(ps[reg], off);
        pd[reg] += __shfl_xor(pd[reg], off);
      }
    }
    if (m == 0) {
#pragma unroll
      for (int reg = 0; reg < 4; ++reg) {
        int row = row0 + wid * 16 + quad * 4 + reg;
        if (row < N_NODES) {
          int idx = t * N_NODES + row;
          a_s[idx] = ps[reg];
          ad_es[idx] = make_float2(pd[reg], leaky(ps[reg] + pd[reg]));  // {a_d, e_self}
        }
      }
    }

    if (t + 1 < NT) {
      __syncthreads();          // all waves done reading Bs
      const unsigned short* Wtt = Wt + (size_t)(t + 1) * C * C;
#pragma unroll
      for (int it = 0; it < 8; ++it) {
        int c = tid + it * 256;
        int n = c >> 4, kc = c & 15;
        *(uint4*)&Bs[n][kc * 8] = *(const uint4*)(Wtt + (size_t)n * C + kc * 8);
      }
      __syncthreads();
    }
  }
}

// ---------------- per node (1 wave): w per lane, denom via wave-reduce, out = self+bias+sum coef*xw ----------------
// Serial loop uses wave-uniform (readfirstlane) bucket-row loads + LDS coefficient
// broadcast instead of 2 ds_bpermute per edge.
__global__ void k_gather(const int* __restrict__ cnt, const int* __restrict__ buckets,
                         const unsigned short* __restrict__ xwb,
                         const float* __restrict__ a_s, const float2* __restrict__ ad_es,
                         const float* __restrict__ bias, float* __restrict__ out) {
  __shared__ float wcs[4][64];
  int wid = threadIdx.x >> 6;
  int lane = threadIdx.x & 63;
  int i = blockIdx.x * 4 + wid;                       // grid covers N exactly (12500*4)
  int iu = __builtin_amdgcn_readfirstlane(i);         // wave-uniform node id
  const int* __restrict__ brow = buckets + (size_t)iu * CAP;
  int n = cnt[iu];
  if (n > CAP) n = CAP;

  int idxl = 0;
  if (lane < n) idxl = brow[lane];                    // coalesced 256B wave load
  int tl = idxl >= 2 * N_NODES ? 2 : (idxl >= N_NODES ? 1 : 0);
  float as = a_s[idxl];                               // random 4B, L2-resident (600 KB)
  float2 am = ad_es[tl * N_NODES + iu];               // 3 distinct addrs per wave
  float wl = (lane < n) ? __expf(leaky(as + am.x) - am.y) : 0.f;

  // per-type denominators: butterfly-reduce w by type
  float s0 = tl == 0 ? wl : 0.f;
  float s1 = tl == 1 ? wl : 0.f;
  float s2 = tl == 2 ? wl : 0.f;
#pragma unroll
  for (int off = 1; off < 64; off <<= 1) {
    s0 += __shfl_xor(s0, off);
    s1 += __shfl_xor(s1, off);
    s2 += __shfl_xor(s2, off);
  }
  float inv3[NT] = {1.f / (s0 + 1.f), 1.f / (s1 + 1.f), 1.f / (s2 + 1.f)};  // w_self == 1
  wcs[wid][lane] = wl * inv3[tl];   // premultiplied coefficient, broadcast via LDS

  // self-loop (coef = inv3[t]) + bias
  float acc0 = 0.f, acc1 = 0.f;   // cols 2*lane, 2*lane+1
#pragma unroll
  for (int t = 0; t < NT; ++t) {
    int idx = t * N_NODES + iu;
    float coef = inv3[t];
    unsigned int w = ((const unsigned int*)(xwb + (size_t)idx * C))[lane];
    float2 b2 = ((const float2*)(bias + t * C))[lane];
    acc0 += coef * bf_lo(w) + b2.x;
    acc1 += coef * bf_hi(w) + b2.y;
  }

  const unsigned int* xwu = (const unsigned int*)xwb;
  int j = 0;
  for (; j + 16 <= n; j += 16) {   // 16-way MLP
    float ac0 = 0.f, ac1 = 0.f;
#pragma unroll
    for (int k = 0; k < 16; ++k) {
      int idx = brow[j + k];          // wave-uniform load (L1-hot line)
      float c = wcs[wid][j + k];      // LDS broadcast, conflict-free
      unsigned int v = xwu[(size_t)idx * (C / 2) + lane];
      ac0 += c * bf_lo(v);
      ac1 += c * bf_hi(v);
    }
    acc0 += ac0; acc1 += ac1;
  }
  for (; j + 8 <= n; j += 8) {     // 8-way MLP
    float ac0 = 0.f, ac1 = 0.f;
#pragma unroll
    for (int k = 0; k < 8; ++k) {
      int idx = brow[j + k];
      float c = wcs[wid][j + k];
      unsigned int v = xwu[(size_t)idx * (C / 2) + lane];
      ac0 += c * bf_lo(v);
      ac1 += c * bf_hi(v);
    }
    acc0 += ac0; acc1 += ac1;
  }
  for (; j < n; ++j) {
    int idx = brow[j];
    float c = wcs[wid][j];
    unsigned int v = xwu[(size_t)idx * (C / 2) + lane];
    acc0 += c * bf_lo(v);
    acc1 += c * bf_hi(v);
  }
  ((float2*)(out + (size_t)iu * C))[lane] = make_float2(acc0, acc1);
}

extern "C" void kernel_launch(void* const* d_in, const int* in_sizes, int n_in,
                              void* d_out, int out_size, void* d_ws, size_t ws_size,
                              hipStream_t stream) {
  const float* x       = (const float*)d_in[0];
  const int* edge_idx  = (const int*)d_in[1];
  const int* edge_type = (const int*)d_in[2];
  const int* node_type = (const int*)d_in[3];
  const float* emb     = (const float*)d_in[4];
  const float* W       = (const float*)d_in[5];
  const float* att_src = (const float*)d_in[6];
  const float* att_dst = (const float*)d_in[7];
  const float* bias    = (const float*)d_in[8];
  float* out = (float*)d_out;

  // workspace layout (~53 MB)
  unsigned short* xwb = (unsigned short*)d_ws;                 // 3*N*C bf16 (38.4 MB)
  unsigned short* Wt  = xwb + (size_t)NT * N_NODES * C;        // 3*C*C bf16 (96 KB)
  float*  a_s   = (float*)(Wt + (size_t)NT * C * C);           // 3*N (600 KB)
  float2* ad_es = (float2*)(a_s + (size_t)NT * N_NODES);       // 3*N float2 (1.2 MB)
  int*    cnt   = (int*)(ad_es + (size_t)NT * N_NODES);        // N ints
  int*    buckets = (int*)(cnt + N_NODES);                     // N*CAP int (12.8 MB)

  k_prep<<<192 + 49, 256, 0, stream>>>(W, Wt, cnt);

  k_bm<<<2 * GEMM_XB, 256, 0, stream>>>(x, node_type, emb, Wt, xwb, att_src, att_dst,
                                        a_s, ad_es, edge_idx, edge_type, cnt, buckets);

  k_gather<<<N_NODES / 4, 256, 0, stream>>>(cnt, buckets, xwb, a_s, ad_es, bias, out);
}